// Round 11
// baseline (199.698 us; speedup 1.0000x reference)
//
#include <hip/hip_runtime.h>
#include <hip/hip_bf16.h>
#include <stdint.h>
#include <math.h>

// Problem constants (fixed by setup_inputs)
#define BATCH 8192   // B rows of embeddings
#define DIM   2048   // D feature dim
#define KDIR  512    // K directions
#define NPTS  17     // quadrature points

typedef _Float16 half8  __attribute__((ext_vector_type(8)));
typedef float   floatx4 __attribute__((ext_vector_type(4)));

#define AS1 __attribute__((address_space(1)))
#define AS3 __attribute__((address_space(3)))

// async global->LDS, 16B per lane. LDS dest must be wave-uniform base + lane*16.
__device__ __forceinline__ void g2l16(const void* g, void* l) {
    __builtin_amdgcn_global_load_lds((AS1 void*)(uintptr_t)g, (AS3 void*)l, 16u, 0, 0u);
}

// ---------------------------------------------------------------------------
// K1: PREP. blocks [0,8192): emb fp32->fp16 (+ zero pp/out in blocks 0-4).
//     blocks [8192,8256): normalize+transpose dir -> dT (coalesced, LDS).
__global__ __launch_bounds__(256) void prep(const float* __restrict__ emb,
                                            const float* __restrict__ dir,
                                            _Float16* __restrict__ A16,
                                            _Float16* __restrict__ dT,
                                            float* __restrict__ pp,
                                            float* __restrict__ out) {
    const int b = blockIdx.x;
    const int t = threadIdx.x;
    if (b < 8192) {
        if (b < 4) pp[b * 256 + t] = 0.f;
        if (b == 4 && t == 0) out[0] = 0.f;
        const size_t i = ((size_t)b * 256 + t) * 8;
        floatx4 a = *(const floatx4*)(emb + i);
        floatx4 c = *(const floatx4*)(emb + i + 4);
        half8 h;
        h[0] = (_Float16)a[0]; h[1] = (_Float16)a[1];
        h[2] = (_Float16)a[2]; h[3] = (_Float16)a[3];
        h[4] = (_Float16)c[0]; h[5] = (_Float16)c[1];
        h[6] = (_Float16)c[2]; h[7] = (_Float16)c[3];
        *(half8*)(A16 + i) = h;
        return;
    }
    const int k0 = (b - 8192) * 8;
    __shared__ _Float16 sv[8][2052];
    __shared__ float    sred[8][32];
    __shared__ float    sinv[8];
    const int g  = t >> 3;
    const int cl = t & 7;
    float ss = 0.f;
    #pragma unroll 8
    for (int it = 0; it < 64; ++it) {
        const int r = it * 32 + g;
        float v = dir[(size_t)r * KDIR + k0 + cl];
        sv[cl][r] = (_Float16)v;
        ss = fmaf(v, v, ss);
    }
    sred[cl][g] = ss;
    __syncthreads();
    if (t < 8) {
        float s = 0.f;
        #pragma unroll
        for (int gg = 0; gg < 32; ++gg) s += sred[t][gg];
        sinv[t] = 1.0f / fmaxf(sqrtf(s), 1e-12f);
    }
    __syncthreads();
    const int c2 = t >> 5;
    const int p  = t & 31;
    const float inv = sinv[c2];
    #pragma unroll
    for (int it2 = 0; it2 < 8; ++it2) {
        const int i0 = p * 8 + it2 * 256;
        half8 h;
        #pragma unroll
        for (int e = 0; e < 8; ++e) h[e] = (_Float16)((float)sv[c2][i0 + e] * inv);
        *(half8*)(dT + (size_t)(k0 + c2) * DIM + i0) = h;
    }
}

// ---------------------------------------------------------------------------
// K2: fp16 MFMA GEMM, BM=256 x BN=256, split-K=4 (k-range 512, 16 BK=32 iters),
// 512 threads (8 waves 4x2, wave tile 64x128 = 4x8 frags). Staged bytes/CU
// drop 1 MB -> 0.5 MB (the measured ~10 B/cyc/CU ingest ceiling is the pin).
// Same vmcnt pipeline as R6/R10. Epilogue: fp32 atomicAdd into zeroed proj.
__global__ __launch_bounds__(512, 2) void gemm_sk(const _Float16* __restrict__ A,
                                                  const _Float16* __restrict__ Bt,
                                                  float* __restrict__ proj) {
    __shared__ _Float16 sA[2][256 * 32];   // [stage][m][k], 64B rows, 16KB/stage
    __shared__ _Float16 sB[2][256 * 32];

    const int tid  = threadIdx.x;
    const int lane = tid & 63;
    const int wave = tid >> 6;
    const int wm = wave & 3;            // 4 wave-rows x 64
    const int wn = wave >> 2;           // 2 wave-cols x 128
    const int tm = blockIdx.x * 256;
    const int tn = blockIdx.y * 256;
    const int k0 = blockIdx.z * (DIM / 4);

    // staging map: seg p = tid + 512*r (r=0,1): row = p>>2, col16 = p&3
    const int r0A = tid >> 2, c0A = (tid & 3) * 8;
    const int r1A = (tid + 512) >> 2, c1A = ((tid + 512) & 3) * 8;
    const _Float16* gA0 = A  + (size_t)(tm + r0A) * DIM + k0 + c0A;
    const _Float16* gA1 = A  + (size_t)(tm + r1A) * DIM + k0 + c1A;
    const _Float16* gB0 = Bt + (size_t)(tn + r0A) * DIM + k0 + c0A;
    const _Float16* gB1 = Bt + (size_t)(tn + r1A) * DIM + k0 + c1A;

#define ISSUE(IT, ST)                                                         \
    do {                                                                      \
        g2l16(gA0 + (IT) * 32, (char*)&sA[ST][0] + tid * 16);                 \
        g2l16(gA1 + (IT) * 32, (char*)&sA[ST][0] + 8192 + tid * 16);          \
        g2l16(gB0 + (IT) * 32, (char*)&sB[ST][0] + tid * 16);                 \
        g2l16(gB1 + (IT) * 32, (char*)&sB[ST][0] + 8192 + tid * 16);          \
    } while (0)

    const floatx4 zero = {0.f, 0.f, 0.f, 0.f};
    floatx4 acc[4][8];
    #pragma unroll
    for (int i = 0; i < 4; ++i)
        #pragma unroll
        for (int j = 0; j < 8; ++j) acc[i][j] = zero;

    const int mrow = lane & 15;
    const int kk   = (lane >> 4) * 8;

    ISSUE(0, 0);

    const int NIT = (DIM / 4) / 32;     // 16
    for (int it = 0; it < NIT; ++it) {
        const int s = it & 1;
        if (it + 1 < NIT) {
            ISSUE(it + 1, (it + 1) & 1);
            asm volatile("s_waitcnt vmcnt(4)" ::: "memory");
        } else {
            asm volatile("s_waitcnt vmcnt(0)" ::: "memory");
        }
        asm volatile("s_barrier" ::: "memory");

        half8 af[4], bf[8];
        #pragma unroll
        for (int f = 0; f < 4; ++f)
            af[f] = *(const half8*)(&sA[s][(size_t)(wm * 64 + f * 16 + mrow) * 32 + kk]);
        #pragma unroll
        for (int g = 0; g < 8; ++g)
            bf[g] = *(const half8*)(&sB[s][(size_t)(wn * 128 + g * 16 + mrow) * 32 + kk]);

        #pragma unroll
        for (int i = 0; i < 4; ++i)
            #pragma unroll
            for (int j = 0; j < 8; ++j)
                acc[i][j] = __builtin_amdgcn_mfma_f32_16x16x32_f16(af[i], bf[j], acc[i][j], 0, 0, 0);

        asm volatile("s_waitcnt lgkmcnt(0)" ::: "memory");
        asm volatile("s_barrier" ::: "memory");
    }
#undef ISSUE

    // C/D layout: col = lane&15, row = (lane>>4)*4 + reg. split-K atomics.
    const int rq = (lane >> 4) * 4;
    const int cn = lane & 15;
    #pragma unroll
    for (int i = 0; i < 4; ++i) {
        #pragma unroll
        for (int j = 0; j < 8; ++j) {
            const int row = tm + wm * 64 + i * 16 + rq;
            const int col = tn + wn * 128 + j * 16 + cn;
            #pragma unroll
            for (int r = 0; r < 4; ++r)
                atomicAdd(&proj[(size_t)(row + r) * KDIR + col], acc[i][j][r]);
        }
    }
}

// ---------------------------------------------------------------------------
// K3: column stats from proj. 128 blocks x 64 rows; thread t owns cols t,t+256.
__global__ __launch_bounds__(256) void stats(const float* __restrict__ proj,
                                             float* __restrict__ pp) {
    const int b = blockIdx.x;
    const int t = threadIdx.x;
    float s0 = 0.f, q0 = 0.f, s1 = 0.f, q1 = 0.f;
    const float* p = proj + (size_t)(b * 64) * KDIR;
    #pragma unroll 8
    for (int r = 0; r < 64; ++r) {
        float v0 = p[(size_t)r * KDIR + t];
        float v1 = p[(size_t)r * KDIR + t + 256];
        s0 += v0; q0 = fmaf(v0, v0, q0);
        s1 += v1; q1 = fmaf(v1, v1, q1);
    }
    atomicAdd(&pp[t], s0);        atomicAdd(&pp[KDIR + t], q0);
    atomicAdd(&pp[t + 256], s1);  atomicAdd(&pp[KDIR + t + 256], q1);
}

// ---------------------------------------------------------------------------
// K4: ECF partials (fp32 proj); mu/isd inline from pp; Chebyshev recurrence.
__global__ __launch_bounds__(256) void ecf_p1(const float* __restrict__ proj,
                                              const float* __restrict__ pp,
                                              float* __restrict__ pecf) {
    const int ch = blockIdx.x >> 1;                      // 0..255
    const int c  = (blockIdx.x & 1) * 256 + threadIdx.x; // 0..511
    const double s_  = (double)pp[c];
    const double s2_ = (double)pp[KDIR + c];
    const double mm  = s_ / (double)BATCH;
    const double var = (s2_ - (double)BATCH * mm * mm) / (double)(BATCH - 1);
    const float m   = (float)mm;
    const float sdi = (float)(1.0 / (sqrt(var) + 1e-8));

    float cr[NPTS], ci[NPTS];
    #pragma unroll
    for (int i = 0; i < NPTS; ++i) { cr[i] = 0.f; ci[i] = 0.f; }
    const float* p = proj + (size_t)(ch * 32) * KDIR + c;
    #pragma unroll 8
    for (int r = 0; r < 32; ++r) {
        float z = (p[(size_t)r * KDIR] - m) * sdi;
        float a = z * (2.0f / 17.0f);
        float s1, c1;
        __sincosf(a, &s1, &c1);
        const float tc = 2.0f * c1;
        float cm = 1.0f, sm = 0.0f;
        float ck = c1,  sk = s1;
        cr[0] += ck; ci[0] += sk;
        #pragma unroll
        for (int k = 1; k < NPTS; ++k) {
            float cn_ = fmaf(tc, ck, -cm);
            float sn_ = fmaf(tc, sk, -sm);
            cm = ck; sm = sk;
            ck = cn_; sk = sn_;
            cr[k] += ck; ci[k] += sk;
        }
    }
    #pragma unroll
    for (int i = 0; i < NPTS; ++i) {
        pecf[(size_t)((ch * NPTS + i) * 2 + 0) * KDIR + c] = cr[i];
        pecf[(size_t)((ch * NPTS + i) * 2 + 1) * KDIR + c] = ci[i];
    }
}

// K5: chunk reduce, one latency round: 544 blocks = 17 i x 16 grp x 2 halves.
__global__ __launch_bounds__(256) void ecf_p2a(const float* __restrict__ pecf,
                                               double* __restrict__ pec2) {
    const int b = blockIdx.x;
    const int i = b >> 5;
    const int r = b & 31;
    const int g = r >> 1;
    const int half = r & 1;
    const int c = half * 256 + threadIdx.x;
    double sc = 0.0, ss = 0.0;
    #pragma unroll
    for (int k = 0; k < 16; ++k) {
        const int ch = g * 16 + k;
        sc += (double)pecf[(size_t)((ch * NPTS + i) * 2 + 0) * KDIR + c];
        ss += (double)pecf[(size_t)((ch * NPTS + i) * 2 + 1) * KDIR + c];
    }
    pec2[(size_t)((i * 16 + g) * 2 + 0) * KDIR + c] = sc;
    pec2[(size_t)((i * 16 + g) * 2 + 1) * KDIR + c] = ss;
}

// K6: finish: sum 16 groups, integrand, block-reduce, atomic.
__global__ __launch_bounds__(256) void ecf_p2b(const double* __restrict__ pec2,
                                               float* __restrict__ out) {
    const int i = blockIdx.x >> 1;
    const int c = (blockIdx.x & 1) * 256 + threadIdx.x;
    double sc = 0.0, ss = 0.0;
    #pragma unroll
    for (int g = 0; g < 16; ++g) {
        sc += pec2[(size_t)((i * 16 + g) * 2 + 0) * KDIR + c];
        ss += pec2[(size_t)((i * 16 + g) * 2 + 1) * KDIR + c];
    }
    const double R = sc / (double)BATCH;
    const double I = ss / (double)BATCH;
    const double t = (2.0 / 17.0) * (double)(i + 1);
    const double tau = exp(-0.5 * t * t);
    const double w = (i == 0 || i == NPTS - 1) ? (1.0 / 17.0) : (2.0 / 17.0);
    const double dR = R - tau;
    double contrib = w * (dR * dR + I * I) / (double)KDIR;

    __shared__ double red[256];
    red[threadIdx.x] = contrib;
    __syncthreads();
    for (int s = 128; s > 0; s >>= 1) {
        if (threadIdx.x < s) red[threadIdx.x] += red[threadIdx.x + s];
        __syncthreads();
    }
    if (threadIdx.x == 0) atomicAdd(out, (float)red[0]);
}

// ---------------------------------------------------------------------------
extern "C" void kernel_launch(void* const* d_in, const int* in_sizes, int n_in,
                              void* d_out, int out_size, void* d_ws, size_t ws_size,
                              hipStream_t stream) {
    const float* emb = (const float*)d_in[0];   // (8192, 2048) fp32
    const float* dir = (const float*)d_in[1];   // (2048, 512) fp32
    float* out = (float*)d_out;

    char* ws = (char*)d_ws;
    // pecf/pec2 alias the A16 region (dead after GEMM).
    _Float16* A16  = (_Float16*)(ws + 0);               // 33,554,432 B
    float*    pecf = (float*)   (ws + 0);               // 17,825,792 B (after GEMM)
    double*   pec2 = (double*)  (ws + 17825792);        //  2,228,224 B (after GEMM)
    _Float16* dT   = (_Float16*)(ws + 33554432);        //  2,097,152 B
    float*    proj = (float*)   (ws + 35651584);        // 16,777,216 B
    float*    pp   = (float*)   (ws + 52428800);        //      4,096 B

    prep<<<8256, 256, 0, stream>>>(emb, dir, A16, dT, pp, out);
    hipMemsetAsync(proj, 0, (size_t)BATCH * KDIR * sizeof(float), stream);
    gemm_sk<<<dim3(BATCH / 256, KDIR / 256, 4), 512, 0, stream>>>(A16, dT, proj);
    stats<<<128, 256, 0, stream>>>(proj, pp);
    ecf_p1<<<512, 256, 0, stream>>>(proj, pp, pecf);
    ecf_p2a<<<544, 256, 0, stream>>>(pecf, pec2);
    ecf_p2b<<<34, 256, 0, stream>>>(pec2, out);
}